// Round 1
// baseline (371.550 us; speedup 1.0000x reference)
//
#include <hip/hip_runtime.h>
#include <math.h>

#define HDIM 256
#define PDIM 256
#define BATCH 8
#define LSEQ 4096
#define MTOT (BATCH * LSEQ)   // 32768
#define NCHUNK 64             // chunks per sequence
#define CHLEN 64              // chunk length (NCHUNK*CHLEN == LSEQ)

// ---------------- param precompute: a, coef=(a-1)/lam, a^CHLEN ----------------
// par layout (floats): [0:512) a  [512:1024) coef  [1024:1536) a^CH   (interleaved r,i)
__global__ void params_k(const float* __restrict__ llr, const float* __restrict__ lim,
                         const float* __restrict__ ldl, float* __restrict__ par) {
    int p = threadIdx.x;
    float er = expf(llr[p]);          // -Re(lam) > 0
    float im = lim[p];
    float d  = expf(ldl[p]);
    float zr = -er * d, zi = im * d;  // lam*delta
    float ea = expf(zr);
    float ar = ea * cosf(zi), ai = ea * sinf(zi);   // a = exp(lam*delta)
    // coef = (a-1)/lam ; lam = (-er, im)
    float dr = -er, di = im;
    float den = dr * dr + di * di;
    float nr = ar - 1.0f, ni = ai;
    float cr = (nr * dr + ni * di) / den;
    float ci = (ni * dr - nr * di) / den;
    // a^CHLEN = exp(CHLEN * lam * delta)
    float e64 = expf((float)CHLEN * zr);
    float s64, c64;
    sincosf((float)CHLEN * zi, &s64, &c64);
    par[2 * p]          = ar;
    par[2 * p + 1]      = ai;
    par[512 + 2 * p]    = cr;
    par[512 + 2 * p + 1] = ci;
    par[1024 + 2 * p]    = e64 * c64;
    par[1024 + 2 * p + 1] = e64 * s64;
}

// W1[h][2p] = Re(coef_p * B_tilde[p][h]); W1[h][2p+1] = Im(...)
__global__ void w1_k(const float* __restrict__ Br, const float* __restrict__ Bi,
                     const float* __restrict__ par, float* __restrict__ W1) {
    int p = blockIdx.x, h = threadIdx.x;
    float cr = par[512 + 2 * p], ci = par[512 + 2 * p + 1];
    float br = Br[p * HDIM + h], bi = Bi[p * HDIM + h];
    W1[h * (2 * PDIM) + 2 * p]     = cr * br - ci * bi;
    W1[h * (2 * PDIM) + 2 * p + 1] = cr * bi + ci * br;
}

// W2[2p][h] = C_real[h][p]; W2[2p+1][h] = -C_imag[h][p]
__global__ void w2_k(const float* __restrict__ Cr, const float* __restrict__ Ci,
                     float* __restrict__ W2) {
    int p = blockIdx.x, h = threadIdx.x;
    W2[(2 * p) * HDIM + h]     = Cr[h * PDIM + p];
    W2[(2 * p + 1) * HDIM + h] = -Ci[h * PDIM + p];
}

// ---------------- LayerNorm row stats: one wave per row ----------------
__global__ void ln_stats_k(const float* __restrict__ u, float2* __restrict__ stats) {
    int lane = threadIdx.x & 63;
    int wv   = threadIdx.x >> 6;
    int row  = blockIdx.x * 4 + wv;
    const float* up = u + (size_t)row * HDIM;
    float4 v = *(const float4*)(up + lane * 4);
    float s  = v.x + v.y + v.z + v.w;
    float sq = v.x * v.x + v.y * v.y + v.z * v.z + v.w * v.w;
    #pragma unroll
    for (int off = 1; off < 64; off <<= 1) {
        s  += __shfl_xor(s, off);
        sq += __shfl_xor(sq, off);
    }
    if (lane == 0) {
        float mu  = s * (1.0f / HDIM);
        float var = sq * (1.0f / HDIM) - mu * mu;
        stats[row] = make_float2(mu, rsqrtf(var + 1e-5f));
    }
}

// ---------------- tiled fp32 GEMM, 128x128 block, 8x8 per thread ----------------
// MODE 0: A = LN(u) applied on the fly (K==256), plain store.
// MODE 1: A = x buffer (plain), epilogue out = u + gelu(acc) (N==256).
#define BM 128
#define BN 128
#define BK 16

template <int MODE>
__launch_bounds__(256, 2)
__global__ void gemm_k(const float* __restrict__ A, const float* __restrict__ W,
                       float* __restrict__ out, const float2* __restrict__ stats,
                       const float* __restrict__ gamma, const float* __restrict__ beta,
                       const float* __restrict__ u, int N, int K) {
    __shared__ float As[BK][BM + 4];
    __shared__ float Bs[BK][BN];
    __shared__ float gS[HDIM], bS[HDIM];

    const int t  = threadIdx.x;
    const int bn = blockIdx.x, bm = blockIdx.y;
    const int tx = t & 15, ty = t >> 4;

    if (MODE == 0) { gS[t] = gamma[t]; bS[t] = beta[t]; }

    const int arow = t >> 1;          // 0..127
    const int acol = (t & 1) * 8;     // 0 or 8
    const int wrow = t >> 4;          // 0..15
    const int wcol = (t & 15) * 8;    // 0..120

    const float* Ap = A + (size_t)(bm * BM + arow) * K;
    float mu = 0.0f, rs = 1.0f;
    if (MODE == 0) {
        float2 st = stats[bm * BM + arow];
        mu = st.x; rs = st.y;
    }

    float acc[8][8] = {};

    for (int k0 = 0; k0 < K; k0 += BK) {
        float4 a0 = *(const float4*)(Ap + k0 + acol);
        float4 a1 = *(const float4*)(Ap + k0 + acol + 4);
        const float* Wp = W + (size_t)(k0 + wrow) * N + bn * BN + wcol;
        float4 w0 = *(const float4*)(Wp);
        float4 w1 = *(const float4*)(Wp + 4);

        __syncthreads();   // previous tile consumed (also covers gS init on iter 0)

        float va[8] = {a0.x, a0.y, a0.z, a0.w, a1.x, a1.y, a1.z, a1.w};
        if (MODE == 0) {
            int c = k0 + acol;
            #pragma unroll
            for (int j = 0; j < 8; j++)
                As[acol + j][arow] = (va[j] - mu) * rs * gS[c + j] + bS[c + j];
        } else {
            #pragma unroll
            for (int j = 0; j < 8; j++) As[acol + j][arow] = va[j];
        }
        *(float4*)&Bs[wrow][wcol]     = w0;
        *(float4*)&Bs[wrow][wcol + 4] = w1;

        __syncthreads();

        #pragma unroll
        for (int kk = 0; kk < BK; kk++) {
            float ra[8], rb[8];
            *(float4*)&ra[0] = *(const float4*)&As[kk][ty * 8];
            *(float4*)&ra[4] = *(const float4*)&As[kk][ty * 8 + 4];
            *(float4*)&rb[0] = *(const float4*)&Bs[kk][tx * 8];
            *(float4*)&rb[4] = *(const float4*)&Bs[kk][tx * 8 + 4];
            #pragma unroll
            for (int i = 0; i < 8; i++)
                #pragma unroll
                for (int j = 0; j < 8; j++)
                    acc[i][j] = fmaf(ra[i], rb[j], acc[i][j]);
        }
    }

    const int orow0 = bm * BM + ty * 8;
    const int ocol0 = bn * BN + tx * 8;
    #pragma unroll
    for (int i = 0; i < 8; i++) {
        float* op = out + (size_t)(orow0 + i) * N + ocol0;
        if (MODE == 1) {
            const float* up = u + (size_t)(orow0 + i) * N + ocol0;
            float r[8];
            #pragma unroll
            for (int j = 0; j < 8; j++) {
                float y = acc[i][j];
                float g = 0.5f * y * (1.0f + tanhf(0.7978845608f * (y + 0.044715f * y * y * y)));
                r[j] = up[j] + g;
            }
            *(float4*)op       = *(float4*)&r[0];
            *(float4*)(op + 4) = *(float4*)&r[4];
        } else {
            float4 s0 = {acc[i][0], acc[i][1], acc[i][2], acc[i][3]};
            float4 s1 = {acc[i][4], acc[i][5], acc[i][6], acc[i][7]};
            *(float4*)op       = s0;
            *(float4*)(op + 4) = s1;
        }
    }
}

// ---------------- chunked diagonal complex scan (in place on Bu) ----------------
// Phase A: per-(b,chunk) block, thread=p, local inclusive scan; store chunk-last.
__global__ void scan_local_k(float* __restrict__ x, const float* __restrict__ par,
                             float* __restrict__ last) {
    int p = threadIdx.x;
    int c = blockIdx.x;   // chunk
    int b = blockIdx.y;
    float ar = par[2 * p], ai = par[2 * p + 1];
    float xr = 0.0f, xi = 0.0f;
    size_t base = ((size_t)b * LSEQ + (size_t)c * CHLEN) * (2 * PDIM) + 2 * p;
    #pragma unroll 8
    for (int j = 0; j < CHLEN; j++) {
        float2 v = *(float2*)(x + base + (size_t)j * (2 * PDIM));
        float nr = fmaf(ar, xr, fmaf(-ai, xi, v.x));
        float ni = fmaf(ar, xi, fmaf(ai, xr, v.y));
        xr = nr; xi = ni;
        *(float2*)(x + base + (size_t)j * (2 * PDIM)) = make_float2(xr, xi);
    }
    *(float2*)(last + ((size_t)b * NCHUNK + c) * (2 * PDIM) + 2 * p) = make_float2(xr, xi);
}

// Phase B: per-(b,p) sequential carry over chunks; prefix[c] = state before chunk c.
__global__ void scan_carry_k(const float* __restrict__ last, float* __restrict__ prefix,
                             const float* __restrict__ par) {
    int p = threadIdx.x;
    int b = blockIdx.x;
    float Ar = par[1024 + 2 * p], Ai = par[1024 + 2 * p + 1];  // a^CHLEN
    float Pr = 0.0f, Pi = 0.0f;
    for (int c = 0; c < NCHUNK; c++) {
        size_t idx = ((size_t)b * NCHUNK + c) * (2 * PDIM) + 2 * p;
        *(float2*)(prefix + idx) = make_float2(Pr, Pi);
        float2 l = *(const float2*)(last + idx);
        float nr = fmaf(Ar, Pr, fmaf(-Ai, Pi, l.x));
        float ni = fmaf(Ar, Pi, fmaf(Ai, Pr, l.y));
        Pr = nr; Pi = ni;
    }
}

// Phase C: x[c*CH+j] += a^{j+1} * prefix[c]
__global__ void scan_apply_k(float* __restrict__ x, const float* __restrict__ par,
                             const float* __restrict__ prefix) {
    int c = blockIdx.x;
    if (c == 0) return;   // prefix is zero
    int p = threadIdx.x;
    int b = blockIdx.y;
    float ar = par[2 * p], ai = par[2 * p + 1];
    float2 Pc = *(const float2*)(prefix + ((size_t)b * NCHUNK + c) * (2 * PDIM) + 2 * p);
    float pwr = ar, pwi = ai;   // a^1
    size_t base = ((size_t)b * LSEQ + (size_t)c * CHLEN) * (2 * PDIM) + 2 * p;
    #pragma unroll 8
    for (int j = 0; j < CHLEN; j++) {
        float2 v = *(float2*)(x + base + (size_t)j * (2 * PDIM));
        v.x = fmaf(pwr, Pc.x, fmaf(-pwi, Pc.y, v.x));
        v.y = fmaf(pwr, Pc.y, fmaf(pwi, Pc.x, v.y));
        *(float2*)(x + base + (size_t)j * (2 * PDIM)) = v;
        float nr = fmaf(pwr, ar, -pwi * ai);
        float ni = fmaf(pwr, ai, pwi * ar);
        pwr = nr; pwi = ni;
    }
}

extern "C" void kernel_launch(void* const* d_in, const int* in_sizes, int n_in,
                              void* d_out, int out_size, void* d_ws, size_t ws_size,
                              hipStream_t stream) {
    const float* u   = (const float*)d_in[0];
    const float* llr = (const float*)d_in[1];
    const float* lim = (const float*)d_in[2];
    const float* Br  = (const float*)d_in[3];
    const float* Bi  = (const float*)d_in[4];
    const float* Cr  = (const float*)d_in[5];
    const float* Ci  = (const float*)d_in[6];
    const float* ldl = (const float*)d_in[7];
    const float* gam = (const float*)d_in[8];
    const float* bet = (const float*)d_in[9];
    float* out = (float*)d_out;

    float* ws     = (float*)d_ws;
    float* par    = ws;                                   // 2048 floats (1536 used)
    float* stats  = ws + 2048;                            // 65536 (32768 float2)
    float* W1     = stats + 65536;                        // 256*512
    float* W2     = W1 + HDIM * 2 * PDIM;                 // 512*256
    float* Bu     = W2 + 2 * PDIM * HDIM;                 // 32768*512 (in-place -> x)
    float* last   = Bu + (size_t)MTOT * 2 * PDIM;         // 8*64*512
    float* prefix = last + (size_t)BATCH * NCHUNK * 2 * PDIM;

    params_k<<<1, PDIM, 0, stream>>>(llr, lim, ldl, par);
    w1_k<<<PDIM, HDIM, 0, stream>>>(Br, Bi, par, W1);
    w2_k<<<PDIM, HDIM, 0, stream>>>(Cr, Ci, W2);
    ln_stats_k<<<MTOT / 4, 256, 0, stream>>>(u, (float2*)stats);

    // GEMM1: Bu[32768][512] = LN(u)[32768][256] @ W1[256][512]
    gemm_k<0><<<dim3(2 * PDIM / BN, MTOT / BM), 256, 0, stream>>>(
        u, W1, Bu, (const float2*)stats, gam, bet, nullptr, 2 * PDIM, HDIM);

    scan_local_k<<<dim3(NCHUNK, BATCH), PDIM, 0, stream>>>(Bu, par, last);
    scan_carry_k<<<BATCH, PDIM, 0, stream>>>(last, prefix, par);
    scan_apply_k<<<dim3(NCHUNK, BATCH), PDIM, 0, stream>>>(Bu, par, prefix);

    // GEMM2: out[32768][256] = u + gelu( x[32768][512] @ W2[512][256] )
    gemm_k<1><<<dim3(HDIM / BN, MTOT / BM), 256, 0, stream>>>(
        Bu, W2, out, nullptr, nullptr, nullptr, u, HDIM, 2 * PDIM);
}

// Round 2
// 175.019 us; speedup vs baseline: 2.1229x; 2.1229x over previous
//
#include <hip/hip_runtime.h>
#include <math.h>

#define HDIM 256
#define PDIM 256
#define BATCH 8
#define LSEQ 4096
#define MTOT (BATCH * LSEQ)   // 32768
#define NCHUNK 128
#define CHLEN 32              // NCHUNK*CHLEN == LSEQ

typedef __attribute__((ext_vector_type(8))) short bf16x8;   // 8 bf16 = 4 VGPRs
typedef __attribute__((ext_vector_type(4))) float f32x4;

__device__ __forceinline__ unsigned short f2bf(float f) {
    union { float f; unsigned int u; } v; v.f = f;
    unsigned int r = v.u + 0x7FFFu + ((v.u >> 16) & 1u);   // RNE
    return (unsigned short)(r >> 16);
}
__device__ __forceinline__ float bf2f(unsigned int lo16) {
    union { unsigned int u; float f; } v; v.u = lo16 << 16;
    return v.f;
}

// ---------------- param precompute: a, coef=(a-1)/lam, a^CHLEN ----------------
// par floats: [0:512) a  [512:1024) coef  [1024:1536) a^CHLEN  (interleaved r,i)
__global__ void params_k(const float* __restrict__ llr, const float* __restrict__ lim,
                         const float* __restrict__ ldl, float* __restrict__ par) {
    int p = threadIdx.x;
    float er = expf(llr[p]);          // -Re(lam) > 0
    float im = lim[p];
    float d  = expf(ldl[p]);
    float zr = -er * d, zi = im * d;  // lam*delta
    float ea = expf(zr);
    float ar = ea * cosf(zi), ai = ea * sinf(zi);   // a = exp(lam*delta)
    float dr = -er, di = im;
    float den = dr * dr + di * di;
    float nr = ar - 1.0f, ni = ai;
    float cr = (nr * dr + ni * di) / den;           // coef = (a-1)/lam
    float ci = (ni * dr - nr * di) / den;
    float eC = expf((float)CHLEN * zr);
    float sC, cC;
    sincosf((float)CHLEN * zi, &sC, &cC);
    par[2 * p]           = ar;
    par[2 * p + 1]       = ai;
    par[512 + 2 * p]     = cr;
    par[512 + 2 * p + 1] = ci;
    par[1024 + 2 * p]     = eC * cC;
    par[1024 + 2 * p + 1] = eC * sC;
}

// W1t[n][k]: n=2p -> Re(coef_p * B_tilde[p][k]); n=2p+1 -> Im. (bf16, [512][256])
__global__ void w1_k(const float* __restrict__ Br, const float* __restrict__ Bi,
                     const float* __restrict__ par, unsigned short* __restrict__ W1t) {
    int p = blockIdx.x, h = threadIdx.x;
    float cr = par[512 + 2 * p], ci = par[512 + 2 * p + 1];
    float br = Br[p * HDIM + h], bi = Bi[p * HDIM + h];
    W1t[(2 * p) * HDIM + h]     = f2bf(cr * br - ci * bi);
    W1t[(2 * p + 1) * HDIM + h] = f2bf(cr * bi + ci * br);
}

// W2t[h][2p] = Cr[h][p]; W2t[h][2p+1] = -Ci[h][p]. (bf16, [256][512])
__global__ void w2_k(const float* __restrict__ Cr, const float* __restrict__ Ci,
                     unsigned short* __restrict__ W2t) {
    int p = blockIdx.x, h = threadIdx.x;
    W2t[h * (2 * PDIM) + 2 * p]     = f2bf(Cr[h * PDIM + p]);
    W2t[h * (2 * PDIM) + 2 * p + 1] = f2bf(-Ci[h * PDIM + p]);
}

// ---------------- fused LayerNorm -> bf16 h ----------------
__global__ void ln_k(const float* __restrict__ u, unsigned short* __restrict__ hbf,
                     const float* __restrict__ gamma, const float* __restrict__ beta) {
    __shared__ float gS[HDIM], bS[HDIM];
    int t = threadIdx.x;
    gS[t] = gamma[t]; bS[t] = beta[t];
    int lane = t & 63, wv = t >> 6;
    int row = blockIdx.x * 4 + wv;
    float4 v = *(const float4*)(u + (size_t)row * HDIM + lane * 4);
    float s  = v.x + v.y + v.z + v.w;
    float sq = v.x * v.x + v.y * v.y + v.z * v.z + v.w * v.w;
    #pragma unroll
    for (int o = 1; o < 64; o <<= 1) { s += __shfl_xor(s, o); sq += __shfl_xor(sq, o); }
    float mu = s * (1.0f / HDIM);
    float rs = rsqrtf(sq * (1.0f / HDIM) - mu * mu + 1e-5f);
    __syncthreads();
    int c = lane * 4;
    ushort4 o;
    o.x = f2bf((v.x - mu) * rs * gS[c + 0] + bS[c + 0]);
    o.y = f2bf((v.y - mu) * rs * gS[c + 1] + bS[c + 1]);
    o.z = f2bf((v.z - mu) * rs * gS[c + 2] + bS[c + 2]);
    o.w = f2bf((v.w - mu) * rs * gS[c + 3] + bS[c + 3]);
    *(ushort4*)(hbf + (size_t)row * HDIM + c) = o;
}

// ---------------- bf16 MFMA GEMM: C[M][N] = A[M][K] * Bt[N][K] ----------------
// 128x128 block, 4 waves in 2x2, each wave 64x64 via 4x4 mfma_f32_16x16x32_bf16.
// MODE 0: store bf16. MODE 1: out fp32 = u + gelu(acc).
#define LDK 40   // padded LDS row stride (elements); 40*2B=80B keeps 16B align, 2-way max bank alias

template <int MODE>
__launch_bounds__(256, 2)
__global__ void mfma_gemm_k(const unsigned short* __restrict__ A,
                            const unsigned short* __restrict__ B,
                            void* __restrict__ outv,
                            const float* __restrict__ u,
                            int N, int K) {
    __shared__ unsigned short As[128 * LDK];
    __shared__ unsigned short Bs[128 * LDK];
    const int t = threadIdx.x;
    const int bn = blockIdx.x, bm = blockIdx.y;
    const int lane = t & 63;
    const int wm = ((t >> 6) & 1) * 64;
    const int wn = ((t >> 6) >> 1) * 64;
    // staging: thread covers row t>>1, k-half (t&1)*16 (32B = two uint4)
    const int srow = t >> 1, skoff = (t & 1) * 16;
    const unsigned short* Ap = A + (size_t)(bm * 128 + srow) * K + skoff;
    const unsigned short* Bp = B + (size_t)(bn * 128 + srow) * K + skoff;
    unsigned short* AsW = &As[srow * LDK + skoff];
    unsigned short* BsW = &Bs[srow * LDK + skoff];
    const int mrow = lane & 15;
    const int kq = (lane >> 4) * 8;

    f32x4 acc[4][4] = {};

    for (int k0 = 0; k0 < K; k0 += 32) {
        uint4 a0 = *(const uint4*)(Ap + k0);
        uint4 a1 = *(const uint4*)(Ap + k0 + 8);
        uint4 b0 = *(const uint4*)(Bp + k0);
        uint4 b1 = *(const uint4*)(Bp + k0 + 8);
        __syncthreads();   // previous tile consumed
        *(uint4*)AsW       = a0;
        *(uint4*)(AsW + 8) = a1;
        *(uint4*)BsW       = b0;
        *(uint4*)(BsW + 8) = b1;
        __syncthreads();
        bf16x8 fa[4], fb[4];
        #pragma unroll
        for (int i = 0; i < 4; i++) {
            fa[i] = *(const bf16x8*)&As[(wm + i * 16 + mrow) * LDK + kq];
            fb[i] = *(const bf16x8*)&Bs[(wn + i * 16 + mrow) * LDK + kq];
        }
        #pragma unroll
        for (int i = 0; i < 4; i++)
            #pragma unroll
            for (int j = 0; j < 4; j++)
                acc[i][j] = __builtin_amdgcn_mfma_f32_16x16x32_bf16(fa[i], fb[j], acc[i][j], 0, 0, 0);
    }

    // C/D layout (m89-verified): col = lane&15, row = (lane>>4)*4 + reg
    const int r0 = (lane >> 4) * 4;
    const int c0 = lane & 15;
    #pragma unroll
    for (int i = 0; i < 4; i++) {
        #pragma unroll
        for (int r = 0; r < 4; r++) {
            const size_t rowoff = (size_t)(bm * 128 + wm + i * 16 + r0 + r) * N;
            #pragma unroll
            for (int j = 0; j < 4; j++) {
                const int col_g = bn * 128 + wn + j * 16 + c0;
                float y = acc[i][j][r];
                if (MODE == 0) {
                    ((unsigned short*)outv)[rowoff + col_g] = f2bf(y);
                } else {
                    float z = 0.7978845608f * fmaf(0.044715f * y * y, y, y);
                    float e = __expf(2.0f * z);
                    float th = 1.0f - 2.0f / (e + 1.0f);
                    float g = 0.5f * y * (1.0f + th);
                    ((float*)outv)[rowoff + col_g] = u[rowoff + col_g] + g;
                }
            }
        }
    }
}

// ---------------- chunked diagonal complex scan over bf16 Bu ----------------
// pass 1: per-(chunk,batch) block, thread=p: chunk-local reduction (no writes to Bu)
__global__ void scan_reduce_k(const unsigned short* __restrict__ Bu,
                              const float* __restrict__ par, float* __restrict__ last) {
    int p = threadIdx.x, c = blockIdx.x, b = blockIdx.y;
    float ar = par[2 * p], ai = par[2 * p + 1];
    float xr = 0.0f, xi = 0.0f;
    const unsigned int* q = (const unsigned int*)(Bu + ((size_t)b * LSEQ + (size_t)c * CHLEN) * 512) + p;
    #pragma unroll 8
    for (int j = 0; j < CHLEN; j++) {
        unsigned int v = q[j * 256];
        float vr = bf2f(v & 0xFFFFu), vi = bf2f(v >> 16);
        float nr = fmaf(ar, xr, fmaf(-ai, xi, vr));
        float ni = fmaf(ar, xi, fmaf(ai, xr, vi));
        xr = nr; xi = ni;
    }
    *(float2*)(last + ((size_t)b * NCHUNK + c) * 512 + 2 * p) = make_float2(xr, xi);
}

// pass 2: per-(b,p) sequential carry across chunks; prefix[c] = state entering chunk c
__global__ void scan_carry_k(const float* __restrict__ last, float* __restrict__ prefix,
                             const float* __restrict__ par) {
    int p = threadIdx.x, b = blockIdx.x;
    float Ar = par[1024 + 2 * p], Ai = par[1024 + 2 * p + 1];  // a^CHLEN
    float Pr = 0.0f, Pi = 0.0f;
    for (int c = 0; c < NCHUNK; c++) {
        size_t idx = ((size_t)b * NCHUNK + c) * 512 + 2 * p;
        *(float2*)(prefix + idx) = make_float2(Pr, Pi);
        float2 l = *(const float2*)(last + idx);
        float nr = fmaf(Ar, Pr, fmaf(-Ai, Pi, l.x));
        float ni = fmaf(Ar, Pi, fmaf(Ai, Pr, l.y));
        Pr = nr; Pi = ni;
    }
}

// pass 3: redo local recursion seeded with prefix, overwrite Bu with x (bf16)
__global__ void scan_apply_k(unsigned short* __restrict__ Bu, const float* __restrict__ par,
                             const float* __restrict__ prefix) {
    int p = threadIdx.x, c = blockIdx.x, b = blockIdx.y;
    float ar = par[2 * p], ai = par[2 * p + 1];
    float2 P = *(const float2*)(prefix + ((size_t)b * NCHUNK + c) * 512 + 2 * p);
    float xr = P.x, xi = P.y;
    unsigned int* q = (unsigned int*)(Bu + ((size_t)b * LSEQ + (size_t)c * CHLEN) * 512) + p;
    #pragma unroll 8
    for (int j = 0; j < CHLEN; j++) {
        unsigned int v = q[j * 256];
        float vr = bf2f(v & 0xFFFFu), vi = bf2f(v >> 16);
        float nr = fmaf(ar, xr, fmaf(-ai, xi, vr));
        float ni = fmaf(ar, xi, fmaf(ai, xr, vi));
        xr = nr; xi = ni;
        q[j * 256] = (unsigned int)f2bf(xr) | ((unsigned int)f2bf(xi) << 16);
    }
}

extern "C" void kernel_launch(void* const* d_in, const int* in_sizes, int n_in,
                              void* d_out, int out_size, void* d_ws, size_t ws_size,
                              hipStream_t stream) {
    const float* u   = (const float*)d_in[0];
    const float* llr = (const float*)d_in[1];
    const float* lim = (const float*)d_in[2];
    const float* Br  = (const float*)d_in[3];
    const float* Bi  = (const float*)d_in[4];
    const float* Cr  = (const float*)d_in[5];
    const float* Ci  = (const float*)d_in[6];
    const float* ldl = (const float*)d_in[7];
    const float* gam = (const float*)d_in[8];
    const float* bet = (const float*)d_in[9];
    float* out = (float*)d_out;

    float* ws     = (float*)d_ws;
    float* par    = ws;                                     // 2048 floats
    float* last   = ws + 2048;                              // 8*128*512 floats (2 MB)
    float* prefix = last + (size_t)BATCH * NCHUNK * 512;    // 2 MB
    unsigned short* W1t = (unsigned short*)(prefix + (size_t)BATCH * NCHUNK * 512);
    unsigned short* W2t = W1t + 512 * HDIM;                 // [256][512]
    unsigned short* hbf = W2t + HDIM * 512;                 // [32768][256] bf16
    unsigned short* Bu  = hbf + (size_t)MTOT * HDIM;        // [32768][512] bf16 (in-place -> x)

    params_k<<<1, PDIM, 0, stream>>>(llr, lim, ldl, par);
    w1_k<<<PDIM, HDIM, 0, stream>>>(Br, Bi, par, W1t);
    w2_k<<<PDIM, HDIM, 0, stream>>>(Cr, Ci, W2t);
    ln_k<<<MTOT / 4, 256, 0, stream>>>(u, hbf, gam, bet);

    // GEMM1: Bu[32768][512] = h[32768][256] @ W1t^T   (bf16 in, bf16 out)
    mfma_gemm_k<0><<<dim3(512 / 128, MTOT / 128), 256, 0, stream>>>(
        hbf, W1t, (void*)Bu, nullptr, 512, HDIM);

    scan_reduce_k<<<dim3(NCHUNK, BATCH), PDIM, 0, stream>>>(Bu, par, last);
    scan_carry_k<<<BATCH, PDIM, 0, stream>>>(last, prefix, par);
    scan_apply_k<<<dim3(NCHUNK, BATCH), PDIM, 0, stream>>>(Bu, par, prefix);

    // GEMM2: out[32768][256] = u + gelu( x[32768][512] @ W2t^T )   (fp32 out)
    mfma_gemm_k<1><<<dim3(HDIM / 128, MTOT / 128), 256, 0, stream>>>(
        Bu, W2t, (void*)out, u, HDIM, 512);
}